// Round 1
// baseline (2103.813 us; speedup 1.0000x reference)
//
#include <hip/hip_runtime.h>
#include <hip/hip_bf16.h>

constexpr int kN    = 100000;
constexpr int kE    = 1600000;
constexpr int kD    = 64;
constexpr int kNF   = 9;
constexpr int kCARD = 16;
constexpr int kBF   = 16;

static_assert(kN % 8 == 0, "node grouping");
static_assert(kE % 64 == 0, "edge tiling");

__device__ __forceinline__ float lane_bcast(float v, int k) {
  return __uint_as_float((unsigned)__builtin_amdgcn_readlane((int)__float_as_uint(v), k));
}
__device__ __forceinline__ float sigm(float v) { return 1.f / (1.f + __expf(-v)); }
__device__ __forceinline__ float tanh_f(float v) { return 1.f - 2.f / (__expf(2.f * v) + 1.f); }

__device__ __forceinline__ unsigned bf16_bits(float v) {
  unsigned u = __float_as_uint(v);
  return (u + 0x7fffu + ((u >> 16) & 1u)) >> 16;
}
__device__ __forceinline__ unsigned pack_bf(float lo, float hi) {
  return bf16_bits(lo) | (bf16_bits(hi) << 16);
}

// ---------- degree ----------
__global__ void k_deg(const int* __restrict__ row, int* __restrict__ cnt) {
  int e = blockIdx.x * blockDim.x + threadIdx.x;
  if (e < kE) atomicAdd(&cnt[row[e]], 1);
}

__global__ void k_dinv(const int* __restrict__ cnt, float* __restrict__ degf,
                       float* __restrict__ dinv) {
  int n = blockIdx.x * blockDim.x + threadIdx.x;
  if (n < kN) {
    float d = (float)cnt[n] + 1.f;
    degf[n] = d;
    dinv[n] = rsqrtf(d);
  }
}

// ---------- edge_attr moments: sumA[16], M = A^T A [16x16] ----------
__global__ __launch_bounds__(256) void k_stats(const float* __restrict__ ea,
                                               float* __restrict__ sumA,
                                               float* __restrict__ Msum) {
  __shared__ float tile[1024];
  int tid = threadIdx.x;
  int i = tid >> 4, j = tid & 15;
  float accM = 0.f, accS = 0.f;
  const int T = kE / 64;
  for (int t = blockIdx.x; t < T; t += gridDim.x) {
    const float4* src = (const float4*)(ea + (size_t)t * 1024);
    ((float4*)tile)[tid] = src[tid];
    __syncthreads();
#pragma unroll 8
    for (int e = 0; e < 64; e++) {
      float aj = tile[e * 16 + j];
      accM += tile[e * 16 + i] * aj;
      if (i == 0) accS += aj;
    }
    __syncthreads();
  }
  atomicAdd(&Msum[i * 16 + j], accM);
  if (i == 0) atomicAdd(&sumA[j], accS);
}

// ---------- fold bond-linear + BN into Weff/beff per layer ----------
__global__ __launch_bounds__(256) void k_bnfold(
    const float* __restrict__ sumA, const float* __restrict__ Msum,
    const float* __restrict__ bond_W, const float* __restrict__ bond_b,
    const float* __restrict__ bond_g, const float* __restrict__ bond_beta,
    float* __restrict__ Weff, float* __restrict__ beff) {
  __shared__ float Ms[256];
  __shared__ float ab[16];
  int tid = threadIdx.x;
  Ms[tid] = Msum[tid] * (1.f / (float)kE);
  if (tid < 16) ab[tid] = sumA[tid] * (1.f / (float)kE);
  __syncthreads();
  if (tid < 192) {
    int l = tid / 64, d = tid % 64;
    const float* W = bond_W + l * kBF * kD;
    float w[16];
#pragma unroll
    for (int k = 0; k < 16; k++) w[k] = W[k * 64 + d];
    float b = bond_b[l * 64 + d];
    float lin = 0.f;
#pragma unroll
    for (int k = 0; k < 16; k++) lin += ab[k] * w[k];
    float mu = lin + b;
    float q = 0.f;
#pragma unroll
    for (int i = 0; i < 16; i++) {
      float wi = w[i];
#pragma unroll
      for (int k = 0; k < 16; k++) q += Ms[i * 16 + k] * wi * w[k];
    }
    float ex2 = q + 2.f * b * lin + b * b;
    float var = ex2 - mu * mu;
    float s = bond_g[l * 64 + d] * rsqrtf(var + 1e-6f);
#pragma unroll
    for (int k = 0; k < 16; k++) Weff[l * 1024 + k * 64 + d] = w[k] * s;
    beff[l * 64 + d] = (b - mu) * s + bond_beta[l * 64 + d];
  }
}

// ---------- encoder: h = [atom_x, sum_f emb] @ projW + b ----------
__global__ __launch_bounds__(256) void k_enc(
    const float* __restrict__ atom_x, const int* __restrict__ feat,
    const float* __restrict__ emb, const float* __restrict__ projW,
    const float* __restrict__ projb, float* __restrict__ h) {
  __shared__ float W[128 * 64];
  int tid = threadIdx.x;
  for (int i = tid; i < 128 * 64 / 4; i += 256)
    ((float4*)W)[i] = ((const float4*)projW)[i];
  __syncthreads();
  int lane = tid & 63, wv = tid >> 6;
  int gw = blockIdx.x * 4 + wv, nw = gridDim.x * 4;
  float bd = projb[lane];
  for (int grp = gw; grp < kN / 4; grp += nw) {
    int n0 = grp * 4;
    float ax[4], x2[4], acc[4];
#pragma unroll
    for (int i = 0; i < 4; i++) {
      int n = n0 + i;
      ax[i] = atom_x[n * kD + lane];
      const int* fr = feat + n * kNF;
      float s = 0.f;
#pragma unroll
      for (int f = 0; f < kNF; f++) {
        int c = fr[f];
        s += emb[(f * kCARD + c) * kD + lane];
      }
      x2[i] = s;
      acc[i] = bd;
    }
#pragma unroll 4
    for (int k = 0; k < kD; k++) {
      float wt = W[k * 64 + lane];
      float wb = W[(64 + k) * 64 + lane];
#pragma unroll
      for (int i = 0; i < 4; i++)
        acc[i] += lane_bcast(ax[i], k) * wt + lane_bcast(x2[i], k) * wb;
    }
#pragma unroll
    for (int i = 0; i < 4; i++) h[(n0 + i) * kD + lane] = acc[i];
  }
}

// ---------- x = BN(h)[opt relu] @ lin_W + lin_b ----------
__global__ __launch_bounds__(256) void k_lin(
    const float* __restrict__ hin, const float* __restrict__ Wg,
    const float* __restrict__ bg, int apply_bn,
    const float* __restrict__ bnsum, const float* __restrict__ bnss,
    const float* __restrict__ bng, const float* __restrict__ bnb,
    float* __restrict__ xout) {
  __shared__ float W[64 * 64];
  int tid = threadIdx.x;
  for (int i = tid; i < 64 * 64 / 4; i += 256)
    ((float4*)W)[i] = ((const float4*)Wg)[i];
  __syncthreads();
  int lane = tid & 63, wv = tid >> 6;
  int gw = blockIdx.x * 4 + wv, nw = gridDim.x * 4;
  float mu = 0.f, sc = 0.f, bb = 0.f;
  if (apply_bn) {
    float m = bnsum[lane] * (1.f / (float)kN);
    float var = bnss[lane] * (1.f / (float)kN) - m * m;
    mu = m;
    sc = rsqrtf(var + 1e-5f) * bng[lane];
    bb = bnb[lane];
  }
  float bd = bg[lane];
  for (int grp = gw; grp < kN / 4; grp += nw) {
    int n0 = grp * 4;
    float hv[4], acc[4];
#pragma unroll
    for (int i = 0; i < 4; i++) {
      float v = hin[(n0 + i) * kD + lane];
      if (apply_bn) v = fmaxf((v - mu) * sc + bb, 0.f);
      hv[i] = v;
      acc[i] = bd;
    }
#pragma unroll 4
    for (int k = 0; k < kD; k++) {
      float w = W[k * 64 + lane];
#pragma unroll
      for (int i = 0; i < 4; i++) acc[i] += lane_bcast(hv[i], k) * w;
    }
#pragma unroll
    for (int i = 0; i < 4; i++) xout[(n0 + i) * kD + lane] = acc[i];
  }
}

// ---------- edge: aggr[col] += norm * relu(x[row] + ea@Weff + beff) ----------
__global__ __launch_bounds__(256) void k_edge(
    const int* __restrict__ row, const int* __restrict__ col,
    const float* __restrict__ ea, const float* __restrict__ x,
    const float* __restrict__ dinv, const float* __restrict__ Weff,
    const float* __restrict__ beff, float* __restrict__ aggr) {
  int tid = threadIdx.x;
  int lane = tid & 63, wv = tid >> 6;
  int gw = blockIdx.x * 4 + wv, nw = gridDim.x * 4;
  float wc[16];
#pragma unroll
  for (int k = 0; k < 16; k++) wc[k] = Weff[k * 64 + lane];
  float be = beff[lane];
  for (int e = gw; e < kE; e += nw) {
    int eu = __builtin_amdgcn_readfirstlane(e);
    int r = row[eu], c = col[eu];
    float nrm = dinv[r] * dinv[c];
    float xj = x[r * kD + lane];
    const float* a = ea + (size_t)eu * kBF;
    float acc = be;
#pragma unroll
    for (int k = 0; k < 16; k++) acc += a[k] * wc[k];
    float m = nrm * fmaxf(xj + acc, 0.f);
    atomicAdd(&aggr[c * kD + lane], m);
  }
}

// ---------- GRU + root term + BN-stat accumulation; writes pre-BN h ----------
__global__ __launch_bounds__(1024) void k_gru(
    const float* __restrict__ aggr, const float* __restrict__ x,
    const float* __restrict__ Wih, const float* __restrict__ Whh,
    const float* __restrict__ bih, const float* __restrict__ bhh,
    const float* __restrict__ root, const float* __restrict__ degf,
    float* __restrict__ h, float* __restrict__ bnsum, float* __restrict__ bnss) {
  // 3 planes of packed-bf16 weight pairs: (ih_r,ih_z) (ih_n,hh_r) (hh_z,hh_n)
  __shared__ unsigned WL[3 * 64 * 64];  // 48 KiB
  int tid = threadIdx.x;
  for (int idx = tid; idx < 64 * 64; idx += 1024) {
    int k = idx >> 6, d = idx & 63;
    float a0 = Wih[(0 * 64 + d) * 64 + k];
    float a1 = Wih[(1 * 64 + d) * 64 + k];
    float a2 = Wih[(2 * 64 + d) * 64 + k];
    float b0 = Whh[(0 * 64 + d) * 64 + k];
    float b1 = Whh[(1 * 64 + d) * 64 + k];
    float b2 = Whh[(2 * 64 + d) * 64 + k];
    WL[idx] = pack_bf(a0, a1);
    WL[4096 + idx] = pack_bf(a2, b0);
    WL[8192 + idx] = pack_bf(b1, b2);
  }
  __syncthreads();
  int lane = tid & 63, wv = tid >> 6;
  int gw = blockIdx.x * 16 + wv, nw = gridDim.x * 16;
  float bi0 = bih[lane], bi1 = bih[64 + lane], bi2 = bih[128 + lane];
  float bh0 = bhh[lane], bh1 = bhh[64 + lane], bh2 = bhh[128 + lane];
  float rt = root[lane];
  float s1 = 0.f, s2 = 0.f;
  for (int grp = gw; grp < kN / 8; grp += nw) {
    int n0 = grp * 8;
    float ag[8], xv[8];
#pragma unroll
    for (int i = 0; i < 8; i++) {
      ag[i] = aggr[(n0 + i) * kD + lane];
      xv[i] = x[(n0 + i) * kD + lane];
    }
    float air[8], aiz[8], ain[8], ahr[8], ahz[8], ahn[8];
#pragma unroll
    for (int i = 0; i < 8; i++) {
      air[i] = bi0; aiz[i] = bi1; ain[i] = bi2;
      ahr[i] = bh0; ahz[i] = bh1; ahn[i] = bh2;
    }
#pragma unroll 2
    for (int k = 0; k < 64; k++) {
      unsigned u0 = WL[k * 64 + lane];
      unsigned u1 = WL[4096 + k * 64 + lane];
      unsigned u2 = WL[8192 + k * 64 + lane];
      float wir = __uint_as_float(u0 << 16);
      float wiz = __uint_as_float(u0 & 0xffff0000u);
      float win = __uint_as_float(u1 << 16);
      float whr = __uint_as_float(u1 & 0xffff0000u);
      float whz = __uint_as_float(u2 << 16);
      float whn = __uint_as_float(u2 & 0xffff0000u);
#pragma unroll
      for (int i = 0; i < 8; i++) {
        float ak = lane_bcast(ag[i], k);
        float xk = lane_bcast(xv[i], k);
        air[i] += ak * wir; aiz[i] += ak * wiz; ain[i] += ak * win;
        ahr[i] += xk * whr; ahz[i] += xk * whz; ahn[i] += xk * whn;
      }
    }
#pragma unroll
    for (int i = 0; i < 8; i++) {
      int n = n0 + i;
      float r = sigm(air[i] + ahr[i]);
      float z = sigm(aiz[i] + ahz[i]);
      float nn = tanh_f(ain[i] + r * ahn[i]);
      float xd = xv[i];
      float upd = (1.f - z) * nn + z * xd;
      float hl = upd + fmaxf(xd + rt, 0.f) / degf[n];
      h[n * kD + lane] = hl;
      s1 += hl;
      s2 += hl * hl;
    }
  }
  __syncthreads();
  float* red = (float*)WL;
  red[wv * 64 + lane] = s1;
  red[1024 + wv * 64 + lane] = s2;
  __syncthreads();
  if (tid < 64) {
    float t1 = 0.f, t2 = 0.f;
#pragma unroll
    for (int w = 0; w < 16; w++) {
      t1 += red[w * 64 + tid];
      t2 += red[1024 + w * 64 + tid];
    }
    atomicAdd(&bnsum[tid], t1);
    atomicAdd(&bnss[tid], t2);
  }
}

// ---------- final BN (layer 2, no relu) -> d_out ----------
__global__ void k_final(const float* __restrict__ h, const float* __restrict__ bnsum,
                        const float* __restrict__ bnss, const float* __restrict__ bng,
                        const float* __restrict__ bnb, float* __restrict__ out) {
  int idx = blockIdx.x * blockDim.x + threadIdx.x;
  if (idx < kN * kD) {
    int d = idx & 63;
    float m = bnsum[d] * (1.f / (float)kN);
    float var = bnss[d] * (1.f / (float)kN) - m * m;
    float sc = rsqrtf(var + 1e-5f) * bng[d];
    out[idx] = (h[idx] - m) * sc + bnb[d];
  }
}

extern "C" void kernel_launch(void* const* d_in, const int* in_sizes, int n_in,
                              void* d_out, int out_size, void* d_ws, size_t ws_size,
                              hipStream_t stream) {
  const float* atom_x       = (const float*)d_in[0];
  const int*   atom_feature = (const int*)d_in[1];
  const int*   edge_index   = (const int*)d_in[2];
  const float* edge_attr    = (const float*)d_in[3];
  const float* atom_emb     = (const float*)d_in[4];
  const float* proj_W       = (const float*)d_in[5];
  const float* proj_b       = (const float*)d_in[6];
  const float* lin_W        = (const float*)d_in[7];
  const float* lin_b        = (const float*)d_in[8];
  const float* root_emb     = (const float*)d_in[9];
  const float* bond_W       = (const float*)d_in[10];
  const float* bond_b       = (const float*)d_in[11];
  const float* bond_g       = (const float*)d_in[12];
  const float* bond_beta    = (const float*)d_in[13];
  const float* gru_Wih      = (const float*)d_in[14];
  const float* gru_bih      = (const float*)d_in[15];
  const float* gru_Whh      = (const float*)d_in[16];
  const float* gru_bhh      = (const float*)d_in[17];
  const float* bn_g         = (const float*)d_in[18];
  const float* bn_b         = (const float*)d_in[19];
  float* out = (float*)d_out;

  const int* row = edge_index;
  const int* col = edge_index + kE;

  float* ws = (float*)d_ws;
  const size_t NH = (size_t)kN * kD;
  float* h     = ws;
  float* x     = ws + NH;
  float* aggr  = ws + 2 * NH;
  float* degf  = ws + 3 * NH;
  float* dinv  = degf + kN;
  int*   cnt   = (int*)(dinv + kN);
  float* sumA  = (float*)(cnt + kN);
  float* Msum  = sumA + 16;
  float* Weff  = Msum + 256;
  float* beff  = Weff + 3 * 16 * 64;
  float* bnsum = beff + 3 * 64;
  float* bnss  = bnsum + 64;

  hipMemsetAsync(cnt, 0, kN * sizeof(int), stream);
  k_deg<<<(kE + 255) / 256, 256, 0, stream>>>(row, cnt);
  k_dinv<<<(kN + 255) / 256, 256, 0, stream>>>(cnt, degf, dinv);
  hipMemsetAsync(sumA, 0, (16 + 256) * sizeof(float), stream);
  k_stats<<<512, 256, 0, stream>>>(edge_attr, sumA, Msum);
  k_bnfold<<<1, 256, 0, stream>>>(sumA, Msum, bond_W, bond_b, bond_g, bond_beta,
                                  Weff, beff);
  k_enc<<<1024, 256, 0, stream>>>(atom_x, atom_feature, atom_emb, proj_W, proj_b, h);

  for (int l = 0; l < 3; l++) {
    const float* pg = (l > 0) ? (bn_g + (l - 1) * 64) : bn_g;
    const float* pb = (l > 0) ? (bn_b + (l - 1) * 64) : bn_b;
    k_lin<<<1024, 256, 0, stream>>>(h, lin_W + l * 64 * 64, lin_b + l * 64,
                                    l > 0 ? 1 : 0, bnsum, bnss, pg, pb, x);
    hipMemsetAsync(aggr, 0, NH * sizeof(float), stream);
    k_edge<<<2048, 256, 0, stream>>>(row, col, edge_attr, x, dinv,
                                     Weff + l * 16 * 64, beff + l * 64, aggr);
    hipMemsetAsync(bnsum, 0, 128 * sizeof(float), stream);
    k_gru<<<256, 1024, 0, stream>>>(aggr, x, gru_Wih + l * 192 * 64,
                                    gru_Whh + l * 192 * 64, gru_bih + l * 192,
                                    gru_bhh + l * 192, root_emb + l * 64, degf, h,
                                    bnsum, bnss);
  }
  k_final<<<(kN * kD + 255) / 256, 256, 0, stream>>>(h, bnsum, bnss, bn_g + 2 * 64,
                                                     bn_b + 2 * 64, out);
}

// Round 2
// 1861.407 us; speedup vs baseline: 1.1302x; 1.1302x over previous
//
#include <hip/hip_runtime.h>
#include <hip/hip_bf16.h>

constexpr int kN    = 100000;
constexpr int kE    = 1600000;
constexpr int kD    = 64;
constexpr int kNF   = 9;
constexpr int kCARD = 16;
constexpr int kBF   = 16;

__device__ __forceinline__ float lane_bcast(float v, int k) {
  return __uint_as_float((unsigned)__builtin_amdgcn_readlane((int)__float_as_uint(v), k));
}
__device__ __forceinline__ float sigm(float v) { return 1.f / (1.f + __expf(-v)); }
__device__ __forceinline__ float tanh_f(float v) { return 1.f - 2.f / (__expf(2.f * v) + 1.f); }

__device__ __forceinline__ unsigned bf16_bits(float v) {
  unsigned u = __float_as_uint(v);
  return (u + 0x7fffu + ((u >> 16) & 1u)) >> 16;
}
__device__ __forceinline__ unsigned pack_bf(float lo, float hi) {
  return bf16_bits(lo) | (bf16_bits(hi) << 16);
}

// ---------- degree counts (row for deg/dinv, col for CSR) ----------
__global__ void k_cnt(const int* __restrict__ row, const int* __restrict__ col,
                      int* __restrict__ cntr, int* __restrict__ cntc) {
  int e = blockIdx.x * blockDim.x + threadIdx.x;
  if (e < kE) {
    atomicAdd(&cntr[row[e]], 1);
    atomicAdd(&cntc[col[e]], 1);
  }
}

__global__ void k_dinv(const int* __restrict__ cnt, float* __restrict__ degf,
                       float* __restrict__ dinv) {
  int n = blockIdx.x * blockDim.x + threadIdx.x;
  if (n < kN) {
    float d = (float)cnt[n] + 1.f;
    degf[n] = d;
    dinv[n] = rsqrtf(d);
  }
}

// ---------- single-block chunked exclusive scan of col counts ----------
__global__ __launch_bounds__(1024) void k_scan(const int* __restrict__ cnt,
                                               int* __restrict__ ptr,
                                               int* __restrict__ fill) {
  __shared__ int part[1024];
  const int CH = (kN + 1023) / 1024;
  int tid = threadIdx.x;
  int lo = tid * CH, hi = min(lo + CH, kN);
  int s = 0;
  for (int i = lo; i < hi; i++) s += cnt[i];
  part[tid] = s;
  __syncthreads();
  for (int off = 1; off < 1024; off <<= 1) {
    int v = (tid >= off) ? part[tid - off] : 0;
    __syncthreads();
    part[tid] += v;
    __syncthreads();
  }
  int base = (tid == 0) ? 0 : part[tid - 1];
  for (int i = lo; i < hi; i++) {
    ptr[i] = base;
    fill[i] = base;
    base += cnt[i];
  }
  if (tid == 1023) ptr[kN] = base;
}

// ---------- scatter (row, eid) into col-sorted order ----------
__global__ void k_scatter(const int* __restrict__ row, const int* __restrict__ col,
                          int* __restrict__ fill, int2* __restrict__ re) {
  int e = blockIdx.x * blockDim.x + threadIdx.x;
  if (e < kE) {
    int c = col[e];
    int p = atomicAdd(&fill[c], 1);
    re[p] = make_int2(row[e], e);
  }
}

// ---------- edge_attr moments: sumA[16], M = A^T A [16x16] ----------
__global__ __launch_bounds__(256) void k_stats(const float* __restrict__ ea,
                                               float* __restrict__ sumA,
                                               float* __restrict__ Msum) {
  __shared__ float tile[1024];
  int tid = threadIdx.x;
  int i = tid >> 4, j = tid & 15;
  float accM = 0.f, accS = 0.f;
  const int T = kE / 64;
  for (int t = blockIdx.x; t < T; t += gridDim.x) {
    const float4* src = (const float4*)(ea + (size_t)t * 1024);
    ((float4*)tile)[tid] = src[tid];
    __syncthreads();
#pragma unroll 8
    for (int e = 0; e < 64; e++) {
      float aj = tile[e * 16 + j];
      accM += tile[e * 16 + i] * aj;
      if (i == 0) accS += aj;
    }
    __syncthreads();
  }
  atomicAdd(&Msum[i * 16 + j], accM);
  if (i == 0) atomicAdd(&sumA[j], accS);
}

// ---------- fold bond-linear + BN into Weff/beff per layer ----------
__global__ __launch_bounds__(256) void k_bnfold(
    const float* __restrict__ sumA, const float* __restrict__ Msum,
    const float* __restrict__ bond_W, const float* __restrict__ bond_b,
    const float* __restrict__ bond_g, const float* __restrict__ bond_beta,
    float* __restrict__ Weff, float* __restrict__ beff) {
  __shared__ float Ms[256];
  __shared__ float ab[16];
  int tid = threadIdx.x;
  Ms[tid] = Msum[tid] * (1.f / (float)kE);
  if (tid < 16) ab[tid] = sumA[tid] * (1.f / (float)kE);
  __syncthreads();
  if (tid < 192) {
    int l = tid / 64, d = tid % 64;
    const float* W = bond_W + l * kBF * kD;
    float w[16];
#pragma unroll
    for (int k = 0; k < 16; k++) w[k] = W[k * 64 + d];
    float b = bond_b[l * 64 + d];
    float lin = 0.f;
#pragma unroll
    for (int k = 0; k < 16; k++) lin += ab[k] * w[k];
    float mu = lin + b;
    float q = 0.f;
#pragma unroll
    for (int i = 0; i < 16; i++) {
      float wi = w[i];
#pragma unroll
      for (int k = 0; k < 16; k++) q += Ms[i * 16 + k] * wi * w[k];
    }
    float ex2 = q + 2.f * b * lin + b * b;
    float var = ex2 - mu * mu;
    float s = bond_g[l * 64 + d] * rsqrtf(var + 1e-6f);
#pragma unroll
    for (int k = 0; k < 16; k++) Weff[l * 1024 + k * 64 + d] = w[k] * s;
    beff[l * 64 + d] = (b - mu) * s + bond_beta[l * 64 + d];
  }
}

// ---------- encoder: h = [atom_x, sum_f emb] @ projW + b ----------
__global__ __launch_bounds__(256) void k_enc(
    const float* __restrict__ atom_x, const int* __restrict__ feat,
    const float* __restrict__ emb, const float* __restrict__ projW,
    const float* __restrict__ projb, float* __restrict__ h) {
  __shared__ float W[128 * 64];
  int tid = threadIdx.x;
  for (int i = tid; i < 128 * 64 / 4; i += 256)
    ((float4*)W)[i] = ((const float4*)projW)[i];
  __syncthreads();
  int lane = tid & 63, wv = tid >> 6;
  int gw = blockIdx.x * 4 + wv, nw = gridDim.x * 4;
  float bd = projb[lane];
  for (int grp = gw; grp < kN / 4; grp += nw) {
    int n0 = grp * 4;
    float ax[4], x2[4], acc[4];
#pragma unroll
    for (int i = 0; i < 4; i++) {
      int n = n0 + i;
      ax[i] = atom_x[n * kD + lane];
      const int* fr = feat + n * kNF;
      float s = 0.f;
#pragma unroll
      for (int f = 0; f < kNF; f++) {
        int c = fr[f];
        s += emb[(f * kCARD + c) * kD + lane];
      }
      x2[i] = s;
      acc[i] = bd;
    }
#pragma unroll 4
    for (int k = 0; k < kD; k++) {
      float wt = W[k * 64 + lane];
      float wb = W[(64 + k) * 64 + lane];
#pragma unroll
      for (int i = 0; i < 4; i++)
        acc[i] += lane_bcast(ax[i], k) * wt + lane_bcast(x2[i], k) * wb;
    }
#pragma unroll
    for (int i = 0; i < 4; i++) h[(n0 + i) * kD + lane] = acc[i];
  }
}

// ---------- x = BN(h)[opt relu] @ lin_W + lin_b ----------
__global__ __launch_bounds__(256) void k_lin(
    const float* __restrict__ hin, const float* __restrict__ Wg,
    const float* __restrict__ bg, int apply_bn,
    const float* __restrict__ bnsum, const float* __restrict__ bnss,
    const float* __restrict__ bng, const float* __restrict__ bnb,
    float* __restrict__ xout) {
  __shared__ float W[64 * 64];
  int tid = threadIdx.x;
  for (int i = tid; i < 64 * 64 / 4; i += 256)
    ((float4*)W)[i] = ((const float4*)Wg)[i];
  __syncthreads();
  int lane = tid & 63, wv = tid >> 6;
  int gw = blockIdx.x * 4 + wv, nw = gridDim.x * 4;
  float mu = 0.f, sc = 0.f, bb = 0.f;
  if (apply_bn) {
    float m = bnsum[lane] * (1.f / (float)kN);
    float var = bnss[lane] * (1.f / (float)kN) - m * m;
    mu = m;
    sc = rsqrtf(var + 1e-5f) * bng[lane];
    bb = bnb[lane];
  }
  float bd = bg[lane];
  for (int grp = gw; grp < kN / 4; grp += nw) {
    int n0 = grp * 4;
    float hv[4], acc[4];
#pragma unroll
    for (int i = 0; i < 4; i++) {
      float v = hin[(n0 + i) * kD + lane];
      if (apply_bn) v = fmaxf((v - mu) * sc + bb, 0.f);
      hv[i] = v;
      acc[i] = bd;
    }
#pragma unroll 4
    for (int k = 0; k < kD; k++) {
      float w = W[k * 64 + lane];
#pragma unroll
      for (int i = 0; i < 4; i++) acc[i] += lane_bcast(hv[i], k) * w;
    }
#pragma unroll
    for (int i = 0; i < 4; i++) xout[(n0 + i) * kD + lane] = acc[i];
  }
}

// ---------- CSR gather: aggr[n] = sum_{e: col[e]=n} norm*relu(x[row]+bond) ----------
__global__ __launch_bounds__(256) void k_aggr(
    const int* __restrict__ ptr, const int2* __restrict__ re,
    const float* __restrict__ ea, const float* __restrict__ x,
    const float* __restrict__ dinv, const float* __restrict__ Weff,
    const float* __restrict__ beff, float* __restrict__ aggr) {
  int lane = threadIdx.x & 63, wv = threadIdx.x >> 6;
  int n = blockIdx.x * 4 + wv;
  if (n >= kN) return;
  float wc[16];
#pragma unroll
  for (int k = 0; k < 16; k++) wc[k] = Weff[k * 64 + lane];
  float be = beff[lane];
  int start = ptr[n], end = ptr[n + 1];
  float dc = dinv[n];
  float acc = 0.f;
  for (int j0 = start; j0 < end; j0 += 64) {
    int j = j0 + lane;
    int2 m = (j < end) ? re[j] : make_int2(0, 0);
    int cnt = min(64, end - j0);
    for (int t = 0; t < cnt; t++) {
      int rt = __builtin_amdgcn_readlane(m.x, t);
      int et = __builtin_amdgcn_readlane(m.y, t);
      float nrm = dc * dinv[rt];
      float xj = x[(size_t)rt * kD + lane];
      const float4* a4 = (const float4*)(ea + (size_t)et * kBF);
      float bond = be;
#pragma unroll
      for (int q = 0; q < 4; q++) {
        float4 a = a4[q];
        bond += a.x * wc[q * 4] + a.y * wc[q * 4 + 1] +
                a.z * wc[q * 4 + 2] + a.w * wc[q * 4 + 3];
      }
      acc += nrm * fmaxf(xj + bond, 0.f);
    }
  }
  aggr[(size_t)n * kD + lane] = acc;
}

// ---------- GRU + root term + BN-stat accumulation; writes pre-BN h ----------
__global__ __launch_bounds__(1024) void k_gru(
    const float* __restrict__ aggr, const float* __restrict__ x,
    const float* __restrict__ Wih, const float* __restrict__ Whh,
    const float* __restrict__ bih, const float* __restrict__ bhh,
    const float* __restrict__ root, const float* __restrict__ degf,
    float* __restrict__ h, float* __restrict__ bnsum, float* __restrict__ bnss) {
  __shared__ unsigned WL[3 * 64 * 64];  // 48 KiB packed bf16 pairs
  int tid = threadIdx.x;
  for (int idx = tid; idx < 64 * 64; idx += 1024) {
    int k = idx >> 6, d = idx & 63;
    float a0 = Wih[(0 * 64 + d) * 64 + k];
    float a1 = Wih[(1 * 64 + d) * 64 + k];
    float a2 = Wih[(2 * 64 + d) * 64 + k];
    float b0 = Whh[(0 * 64 + d) * 64 + k];
    float b1 = Whh[(1 * 64 + d) * 64 + k];
    float b2 = Whh[(2 * 64 + d) * 64 + k];
    WL[idx] = pack_bf(a0, a1);
    WL[4096 + idx] = pack_bf(a2, b0);
    WL[8192 + idx] = pack_bf(b1, b2);
  }
  __syncthreads();
  int lane = tid & 63, wv = tid >> 6;
  int gw = blockIdx.x * 16 + wv, nw = gridDim.x * 16;
  float bi0 = bih[lane], bi1 = bih[64 + lane], bi2 = bih[128 + lane];
  float bh0 = bhh[lane], bh1 = bhh[64 + lane], bh2 = bhh[128 + lane];
  float rt = root[lane];
  float s1 = 0.f, s2 = 0.f;
  for (int grp = gw; grp < kN / 8; grp += nw) {
    int n0 = grp * 8;
    float ag[8], xv[8];
#pragma unroll
    for (int i = 0; i < 8; i++) {
      ag[i] = aggr[(n0 + i) * kD + lane];
      xv[i] = x[(n0 + i) * kD + lane];
    }
    float air[8], aiz[8], ain[8], ahr[8], ahz[8], ahn[8];
#pragma unroll
    for (int i = 0; i < 8; i++) {
      air[i] = bi0; aiz[i] = bi1; ain[i] = bi2;
      ahr[i] = bh0; ahz[i] = bh1; ahn[i] = bh2;
    }
#pragma unroll 2
    for (int k = 0; k < 64; k++) {
      unsigned u0 = WL[k * 64 + lane];
      unsigned u1 = WL[4096 + k * 64 + lane];
      unsigned u2 = WL[8192 + k * 64 + lane];
      float wir = __uint_as_float(u0 << 16);
      float wiz = __uint_as_float(u0 & 0xffff0000u);
      float win = __uint_as_float(u1 << 16);
      float whr = __uint_as_float(u1 & 0xffff0000u);
      float whz = __uint_as_float(u2 << 16);
      float whn = __uint_as_float(u2 & 0xffff0000u);
#pragma unroll
      for (int i = 0; i < 8; i++) {
        float ak = lane_bcast(ag[i], k);
        float xk = lane_bcast(xv[i], k);
        air[i] += ak * wir; aiz[i] += ak * wiz; ain[i] += ak * win;
        ahr[i] += xk * whr; ahz[i] += xk * whz; ahn[i] += xk * whn;
      }
    }
#pragma unroll
    for (int i = 0; i < 8; i++) {
      int n = n0 + i;
      float r = sigm(air[i] + ahr[i]);
      float z = sigm(aiz[i] + ahz[i]);
      float nn = tanh_f(ain[i] + r * ahn[i]);
      float xd = xv[i];
      float upd = (1.f - z) * nn + z * xd;
      float hl = upd + fmaxf(xd + rt, 0.f) / degf[n];
      h[n * kD + lane] = hl;
      s1 += hl;
      s2 += hl * hl;
    }
  }
  __syncthreads();
  float* red = (float*)WL;
  red[wv * 64 + lane] = s1;
  red[1024 + wv * 64 + lane] = s2;
  __syncthreads();
  if (tid < 64) {
    float t1 = 0.f, t2 = 0.f;
#pragma unroll
    for (int w = 0; w < 16; w++) {
      t1 += red[w * 64 + tid];
      t2 += red[1024 + w * 64 + tid];
    }
    atomicAdd(&bnsum[tid], t1);
    atomicAdd(&bnss[tid], t2);
  }
}

// ---------- final BN (layer 2, no relu) -> d_out ----------
__global__ void k_final(const float* __restrict__ h, const float* __restrict__ bnsum,
                        const float* __restrict__ bnss, const float* __restrict__ bng,
                        const float* __restrict__ bnb, float* __restrict__ out) {
  int idx = blockIdx.x * blockDim.x + threadIdx.x;
  if (idx < kN * kD) {
    int d = idx & 63;
    float m = bnsum[d] * (1.f / (float)kN);
    float var = bnss[d] * (1.f / (float)kN) - m * m;
    float sc = rsqrtf(var + 1e-5f) * bng[d];
    out[idx] = (h[idx] - m) * sc + bnb[d];
  }
}

extern "C" void kernel_launch(void* const* d_in, const int* in_sizes, int n_in,
                              void* d_out, int out_size, void* d_ws, size_t ws_size,
                              hipStream_t stream) {
  const float* atom_x       = (const float*)d_in[0];
  const int*   atom_feature = (const int*)d_in[1];
  const int*   edge_index   = (const int*)d_in[2];
  const float* edge_attr    = (const float*)d_in[3];
  const float* atom_emb     = (const float*)d_in[4];
  const float* proj_W       = (const float*)d_in[5];
  const float* proj_b       = (const float*)d_in[6];
  const float* lin_W        = (const float*)d_in[7];
  const float* lin_b        = (const float*)d_in[8];
  const float* root_emb     = (const float*)d_in[9];
  const float* bond_W       = (const float*)d_in[10];
  const float* bond_b       = (const float*)d_in[11];
  const float* bond_g       = (const float*)d_in[12];
  const float* bond_beta    = (const float*)d_in[13];
  const float* gru_Wih      = (const float*)d_in[14];
  const float* gru_bih      = (const float*)d_in[15];
  const float* gru_Whh      = (const float*)d_in[16];
  const float* gru_bhh      = (const float*)d_in[17];
  const float* bn_g         = (const float*)d_in[18];
  const float* bn_b         = (const float*)d_in[19];
  float* out = (float*)d_out;

  const int* row = edge_index;
  const int* col = edge_index + kE;

  float* ws = (float*)d_ws;
  const size_t NH = (size_t)kN * kD;
  float* h     = ws;
  float* x     = ws + NH;
  float* aggr  = ws + 2 * NH;
  float* degf  = ws + 3 * NH;           // kN
  float* dinv  = degf + kN;             // kN
  int*   cntr  = (int*)(dinv + kN);     // kN
  int*   cntc  = cntr + kN;             // kN
  int*   ptr   = cntc + kN;             // kN+1
  int*   fill  = ptr + kN + 2;          // kN  (keep next offset even)
  int2*  re    = (int2*)(fill + kN);    // kE int2 (8B-aligned: offset even)
  float* sumA  = (float*)(re + kE);     // 16
  float* Msum  = sumA + 16;             // 256
  float* Weff  = Msum + 256;            // 3*1024
  float* beff  = Weff + 3 * 1024;       // 192
  float* bnsum = beff + 192;            // 64
  float* bnss  = bnsum + 64;            // 64

  hipMemsetAsync(cntr, 0, 2 * kN * sizeof(int), stream);
  k_cnt<<<(kE + 255) / 256, 256, 0, stream>>>(row, col, cntr, cntc);
  k_dinv<<<(kN + 255) / 256, 256, 0, stream>>>(cntr, degf, dinv);
  k_scan<<<1, 1024, 0, stream>>>(cntc, ptr, fill);
  k_scatter<<<(kE + 255) / 256, 256, 0, stream>>>(row, col, fill, re);

  hipMemsetAsync(sumA, 0, (16 + 256) * sizeof(float), stream);
  k_stats<<<512, 256, 0, stream>>>(edge_attr, sumA, Msum);
  k_bnfold<<<1, 256, 0, stream>>>(sumA, Msum, bond_W, bond_b, bond_g, bond_beta,
                                  Weff, beff);
  k_enc<<<1024, 256, 0, stream>>>(atom_x, atom_feature, atom_emb, proj_W, proj_b, h);

  for (int l = 0; l < 3; l++) {
    const float* pg = (l > 0) ? (bn_g + (l - 1) * 64) : bn_g;
    const float* pb = (l > 0) ? (bn_b + (l - 1) * 64) : bn_b;
    k_lin<<<1024, 256, 0, stream>>>(h, lin_W + l * 64 * 64, lin_b + l * 64,
                                    l > 0 ? 1 : 0, bnsum, bnss, pg, pb, x);
    k_aggr<<<(kN + 3) / 4, 256, 0, stream>>>(ptr, re, edge_attr, x, dinv,
                                             Weff + l * 1024, beff + l * 64, aggr);
    hipMemsetAsync(bnsum, 0, 128 * sizeof(float), stream);
    k_gru<<<256, 1024, 0, stream>>>(aggr, x, gru_Wih + l * 192 * 64,
                                    gru_Whh + l * 192 * 64, gru_bih + l * 192,
                                    gru_bhh + l * 192, root_emb + l * 64, degf, h,
                                    bnsum, bnss);
  }
  k_final<<<(kN * kD + 255) / 256, 256, 0, stream>>>(h, bnsum, bnss, bn_g + 2 * 64,
                                                     bn_b + 2 * 64, out);
}

// Round 3
// 1647.540 us; speedup vs baseline: 1.2769x; 1.1298x over previous
//
#include <hip/hip_runtime.h>
#include <hip/hip_bf16.h>

constexpr int kN    = 100000;
constexpr int kE    = 1600000;
constexpr int kD    = 64;
constexpr int kNF   = 9;
constexpr int kCARD = 16;
constexpr int kBF   = 16;
constexpr int kScanBlocks = (kN + 1023) / 1024;  // 98

__device__ __forceinline__ float lane_bcast(float v, int k) {
  return __uint_as_float((unsigned)__builtin_amdgcn_readlane((int)__float_as_uint(v), k));
}
__device__ __forceinline__ float sigm(float v) { return 1.f / (1.f + __expf(-v)); }
__device__ __forceinline__ float tanh_f(float v) { return 1.f - 2.f / (__expf(2.f * v) + 1.f); }

__device__ __forceinline__ unsigned bf16_bits(float v) {
  unsigned u = __float_as_uint(v);
  return (u + 0x7fffu + ((u >> 16) & 1u)) >> 16;
}
__device__ __forceinline__ unsigned pack_bf(float lo, float hi) {
  return bf16_bits(lo) | (bf16_bits(hi) << 16);
}

// ---------- degree counts (row for deg/dinv, col for CSR) ----------
__global__ void k_cnt(const int* __restrict__ row, const int* __restrict__ col,
                      int* __restrict__ cntr, int* __restrict__ cntc) {
  int e = blockIdx.x * blockDim.x + threadIdx.x;
  if (e < kE) {
    atomicAdd(&cntr[row[e]], 1);
    atomicAdd(&cntc[col[e]], 1);
  }
}

__global__ void k_dinv(const int* __restrict__ cnt, float* __restrict__ degf,
                       float* __restrict__ dinv) {
  int n = blockIdx.x * blockDim.x + threadIdx.x;
  if (n < kN) {
    float d = (float)cnt[n] + 1.f;
    degf[n] = d;
    dinv[n] = rsqrtf(d);
  }
}

// ---------- multi-block exclusive scan of col counts ----------
__global__ __launch_bounds__(1024) void k_scanA(const int* __restrict__ cnt,
                                                int* __restrict__ loc,
                                                int* __restrict__ bsum) {
  __shared__ int part[1024];
  int tid = threadIdx.x;
  int i = blockIdx.x * 1024 + tid;
  int v = (i < kN) ? cnt[i] : 0;
  part[tid] = v;
  __syncthreads();
  for (int off = 1; off < 1024; off <<= 1) {
    int t = (tid >= off) ? part[tid - off] : 0;
    __syncthreads();
    part[tid] += t;
    __syncthreads();
  }
  if (i < kN) loc[i] = part[tid] - v;  // local exclusive
  if (tid == 1023) bsum[blockIdx.x] = part[1023];
}

__global__ __launch_bounds__(128) void k_scanB(const int* __restrict__ bsum,
                                               int* __restrict__ boff) {
  __shared__ int p[128];
  int tid = threadIdx.x;
  int v = (tid < kScanBlocks) ? bsum[tid] : 0;
  p[tid] = v;
  __syncthreads();
  for (int off = 1; off < 128; off <<= 1) {
    int t = (tid >= off) ? p[tid - off] : 0;
    __syncthreads();
    p[tid] += t;
    __syncthreads();
  }
  boff[tid] = p[tid] - v;  // exclusive
}

__global__ __launch_bounds__(1024) void k_scanC(const int* __restrict__ loc,
                                                const int* __restrict__ boff,
                                                int* __restrict__ ptr,
                                                int* __restrict__ fill) {
  int i = blockIdx.x * 1024 + threadIdx.x;
  if (i < kN) {
    int v = loc[i] + boff[blockIdx.x];
    ptr[i] = v;
    fill[i] = v;
  }
  if (i == 0) ptr[kN] = kE;  // grand total is statically kE
}

// ---------- scatter (row, eid) into col-sorted order ----------
__global__ void k_scatter(const int* __restrict__ row, const int* __restrict__ col,
                          int* __restrict__ fill, int2* __restrict__ re) {
  int e = blockIdx.x * blockDim.x + threadIdx.x;
  if (e < kE) {
    int c = col[e];
    int p = atomicAdd(&fill[c], 1);
    re[p] = make_int2(row[e], e);
  }
}

// ---------- edge_attr moments: sumA[16], M = A^T A [16x16] ----------
__global__ __launch_bounds__(256) void k_stats(const float* __restrict__ ea,
                                               float* __restrict__ sumA,
                                               float* __restrict__ Msum) {
  __shared__ float tile[1024];
  int tid = threadIdx.x;
  int i = tid >> 4, j = tid & 15;
  float accM = 0.f, accS = 0.f;
  const int T = kE / 64;
  for (int t = blockIdx.x; t < T; t += gridDim.x) {
    const float4* src = (const float4*)(ea + (size_t)t * 1024);
    ((float4*)tile)[tid] = src[tid];
    __syncthreads();
#pragma unroll 8
    for (int e = 0; e < 64; e++) {
      float aj = tile[e * 16 + j];
      accM += tile[e * 16 + i] * aj;
      if (i == 0) accS += aj;
    }
    __syncthreads();
  }
  atomicAdd(&Msum[i * 16 + j], accM);
  if (i == 0) atomicAdd(&sumA[j], accS);
}

// ---------- fold bond-linear + BN into Weff/beff per layer ----------
__global__ __launch_bounds__(256) void k_bnfold(
    const float* __restrict__ sumA, const float* __restrict__ Msum,
    const float* __restrict__ bond_W, const float* __restrict__ bond_b,
    const float* __restrict__ bond_g, const float* __restrict__ bond_beta,
    float* __restrict__ Weff, float* __restrict__ beff) {
  __shared__ float Ms[256];
  __shared__ float ab[16];
  int tid = threadIdx.x;
  Ms[tid] = Msum[tid] * (1.f / (float)kE);
  if (tid < 16) ab[tid] = sumA[tid] * (1.f / (float)kE);
  __syncthreads();
  if (tid < 192) {
    int l = tid / 64, d = tid % 64;
    const float* W = bond_W + l * kBF * kD;
    float w[16];
#pragma unroll
    for (int k = 0; k < 16; k++) w[k] = W[k * 64 + d];
    float b = bond_b[l * 64 + d];
    float lin = 0.f;
#pragma unroll
    for (int k = 0; k < 16; k++) lin += ab[k] * w[k];
    float mu = lin + b;
    float q = 0.f;
#pragma unroll
    for (int i = 0; i < 16; i++) {
      float wi = w[i];
#pragma unroll
      for (int k = 0; k < 16; k++) q += Ms[i * 16 + k] * wi * w[k];
    }
    float ex2 = q + 2.f * b * lin + b * b;
    float var = ex2 - mu * mu;
    float s = bond_g[l * 64 + d] * rsqrtf(var + 1e-6f);
#pragma unroll
    for (int k = 0; k < 16; k++) Weff[l * 1024 + k * 64 + d] = w[k] * s;
    beff[l * 64 + d] = (b - mu) * s + bond_beta[l * 64 + d];
  }
}

// ---------- encoder: h = [atom_x, sum_f emb] @ projW + b ----------
__global__ __launch_bounds__(256) void k_enc(
    const float* __restrict__ atom_x, const int* __restrict__ feat,
    const float* __restrict__ emb, const float* __restrict__ projW,
    const float* __restrict__ projb, float* __restrict__ h) {
  __shared__ float W[128 * 64];
  int tid = threadIdx.x;
  for (int i = tid; i < 128 * 64 / 4; i += 256)
    ((float4*)W)[i] = ((const float4*)projW)[i];
  __syncthreads();
  int lane = tid & 63, wv = tid >> 6;
  int gw = blockIdx.x * 4 + wv, nw = gridDim.x * 4;
  float bd = projb[lane];
  for (int grp = gw; grp < kN / 4; grp += nw) {
    int n0 = grp * 4;
    float ax[4], x2[4], acc[4];
#pragma unroll
    for (int i = 0; i < 4; i++) {
      int n = n0 + i;
      ax[i] = atom_x[n * kD + lane];
      const int* fr = feat + n * kNF;
      float s = 0.f;
#pragma unroll
      for (int f = 0; f < kNF; f++) {
        int c = fr[f];
        s += emb[(f * kCARD + c) * kD + lane];
      }
      x2[i] = s;
      acc[i] = bd;
    }
#pragma unroll 4
    for (int k = 0; k < kD; k++) {
      float wt = W[k * 64 + lane];
      float wb = W[(64 + k) * 64 + lane];
#pragma unroll
      for (int i = 0; i < 4; i++)
        acc[i] += lane_bcast(ax[i], k) * wt + lane_bcast(x2[i], k) * wb;
    }
#pragma unroll
    for (int i = 0; i < 4; i++) h[(n0 + i) * kD + lane] = acc[i];
  }
}

// ---------- x = BN(h)[opt relu] @ lin_W + lin_b ----------
__global__ __launch_bounds__(256) void k_lin(
    const float* __restrict__ hin, const float* __restrict__ Wg,
    const float* __restrict__ bg, int apply_bn,
    const float* __restrict__ bnsum, const float* __restrict__ bnss,
    const float* __restrict__ bng, const float* __restrict__ bnb,
    float* __restrict__ xout) {
  __shared__ float W[64 * 64];
  int tid = threadIdx.x;
  for (int i = tid; i < 64 * 64 / 4; i += 256)
    ((float4*)W)[i] = ((const float4*)Wg)[i];
  __syncthreads();
  int lane = tid & 63, wv = tid >> 6;
  int gw = blockIdx.x * 4 + wv, nw = gridDim.x * 4;
  float mu = 0.f, sc = 0.f, bb = 0.f;
  if (apply_bn) {
    float m = bnsum[lane] * (1.f / (float)kN);
    float var = bnss[lane] * (1.f / (float)kN) - m * m;
    mu = m;
    sc = rsqrtf(var + 1e-5f) * bng[lane];
    bb = bnb[lane];
  }
  float bd = bg[lane];
  for (int grp = gw; grp < kN / 4; grp += nw) {
    int n0 = grp * 4;
    float hv[4], acc[4];
#pragma unroll
    for (int i = 0; i < 4; i++) {
      float v = hin[(n0 + i) * kD + lane];
      if (apply_bn) v = fmaxf((v - mu) * sc + bb, 0.f);
      hv[i] = v;
      acc[i] = bd;
    }
#pragma unroll 4
    for (int k = 0; k < kD; k++) {
      float w = W[k * 64 + lane];
#pragma unroll
      for (int i = 0; i < 4; i++) acc[i] += lane_bcast(hv[i], k) * w;
    }
#pragma unroll
    for (int i = 0; i < 4; i++) xout[(n0 + i) * kD + lane] = acc[i];
  }
}

// ---------- CSR gather: aggr[n] = sum_{e: col[e]=n} norm*relu(x[row]+bond) ----------
__global__ __launch_bounds__(256) void k_aggr(
    const int* __restrict__ ptr, const int2* __restrict__ re,
    const float* __restrict__ ea, const float* __restrict__ x,
    const float* __restrict__ dinv, const float* __restrict__ Weff,
    const float* __restrict__ beff, float* __restrict__ aggr) {
  int lane = threadIdx.x & 63, wv = threadIdx.x >> 6;
  int n = blockIdx.x * 4 + wv;
  if (n >= kN) return;
  float wc[16];
#pragma unroll
  for (int k = 0; k < 16; k++) wc[k] = Weff[k * 64 + lane];
  float be = beff[lane];
  int start = ptr[n], end = ptr[n + 1];
  float dc = dinv[n];
  float acc = 0.f;
  for (int j0 = start; j0 < end; j0 += 64) {
    int j = j0 + lane;
    int2 m = (j < end) ? re[j] : make_int2(0, 0);
    int cnt = min(64, end - j0);
    for (int t = 0; t < cnt; t++) {
      int rt = __builtin_amdgcn_readlane(m.x, t);
      int et = __builtin_amdgcn_readlane(m.y, t);
      float nrm = dc * dinv[rt];
      float xj = x[(size_t)rt * kD + lane];
      const float4* a4 = (const float4*)(ea + (size_t)et * kBF);
      float bond = be;
#pragma unroll
      for (int q = 0; q < 4; q++) {
        float4 a = a4[q];
        bond += a.x * wc[q * 4] + a.y * wc[q * 4 + 1] +
                a.z * wc[q * 4 + 2] + a.w * wc[q * 4 + 3];
      }
      acc += nrm * fmaxf(xj + bond, 0.f);
    }
  }
  aggr[(size_t)n * kD + lane] = acc;
}

// ---------- GRU + root term + BN-stat accumulation; writes pre-BN h ----------
__global__ __launch_bounds__(1024) void k_gru(
    const float* __restrict__ aggr, const float* __restrict__ x,
    const float* __restrict__ Wih, const float* __restrict__ Whh,
    const float* __restrict__ bih, const float* __restrict__ bhh,
    const float* __restrict__ root, const float* __restrict__ degf,
    float* __restrict__ h, float* __restrict__ bnsum, float* __restrict__ bnss) {
  __shared__ unsigned WL[3 * 64 * 64];  // 48 KiB packed bf16 pairs
  int tid = threadIdx.x;
  for (int idx = tid; idx < 64 * 64; idx += 1024) {
    int k = idx >> 6, d = idx & 63;
    float a0 = Wih[(0 * 64 + d) * 64 + k];
    float a1 = Wih[(1 * 64 + d) * 64 + k];
    float a2 = Wih[(2 * 64 + d) * 64 + k];
    float b0 = Whh[(0 * 64 + d) * 64 + k];
    float b1 = Whh[(1 * 64 + d) * 64 + k];
    float b2 = Whh[(2 * 64 + d) * 64 + k];
    WL[idx] = pack_bf(a0, a1);
    WL[4096 + idx] = pack_bf(a2, b0);
    WL[8192 + idx] = pack_bf(b1, b2);
  }
  __syncthreads();
  int lane = tid & 63, wv = tid >> 6;
  int gw = blockIdx.x * 16 + wv, nw = gridDim.x * 16;
  float bi0 = bih[lane], bi1 = bih[64 + lane], bi2 = bih[128 + lane];
  float bh0 = bhh[lane], bh1 = bhh[64 + lane], bh2 = bhh[128 + lane];
  float rt = root[lane];
  float s1 = 0.f, s2 = 0.f;
  for (int grp = gw; grp < kN / 8; grp += nw) {
    int n0 = grp * 8;
    float ag[8], xv[8];
#pragma unroll
    for (int i = 0; i < 8; i++) {
      ag[i] = aggr[(n0 + i) * kD + lane];
      xv[i] = x[(n0 + i) * kD + lane];
    }
    float air[8], aiz[8], ain[8], ahr[8], ahz[8], ahn[8];
#pragma unroll
    for (int i = 0; i < 8; i++) {
      air[i] = bi0; aiz[i] = bi1; ain[i] = bi2;
      ahr[i] = bh0; ahz[i] = bh1; ahn[i] = bh2;
    }
#pragma unroll 2
    for (int k = 0; k < 64; k++) {
      unsigned u0 = WL[k * 64 + lane];
      unsigned u1 = WL[4096 + k * 64 + lane];
      unsigned u2 = WL[8192 + k * 64 + lane];
      float wir = __uint_as_float(u0 << 16);
      float wiz = __uint_as_float(u0 & 0xffff0000u);
      float win = __uint_as_float(u1 << 16);
      float whr = __uint_as_float(u1 & 0xffff0000u);
      float whz = __uint_as_float(u2 << 16);
      float whn = __uint_as_float(u2 & 0xffff0000u);
#pragma unroll
      for (int i = 0; i < 8; i++) {
        float ak = lane_bcast(ag[i], k);
        float xk = lane_bcast(xv[i], k);
        air[i] += ak * wir; aiz[i] += ak * wiz; ain[i] += ak * win;
        ahr[i] += xk * whr; ahz[i] += xk * whz; ahn[i] += xk * whn;
      }
    }
#pragma unroll
    for (int i = 0; i < 8; i++) {
      int n = n0 + i;
      float r = sigm(air[i] + ahr[i]);
      float z = sigm(aiz[i] + ahz[i]);
      float nn = tanh_f(ain[i] + r * ahn[i]);
      float xd = xv[i];
      float upd = (1.f - z) * nn + z * xd;
      float hl = upd + fmaxf(xd + rt, 0.f) / degf[n];
      h[n * kD + lane] = hl;
      s1 += hl;
      s2 += hl * hl;
    }
  }
  __syncthreads();
  float* red = (float*)WL;
  red[wv * 64 + lane] = s1;
  red[1024 + wv * 64 + lane] = s2;
  __syncthreads();
  if (tid < 64) {
    float t1 = 0.f, t2 = 0.f;
#pragma unroll
    for (int w = 0; w < 16; w++) {
      t1 += red[w * 64 + tid];
      t2 += red[1024 + w * 64 + tid];
    }
    atomicAdd(&bnsum[tid], t1);
    atomicAdd(&bnss[tid], t2);
  }
}

// ---------- final BN (layer 2, no relu) -> d_out ----------
__global__ void k_final(const float* __restrict__ h, const float* __restrict__ bnsum,
                        const float* __restrict__ bnss, const float* __restrict__ bng,
                        const float* __restrict__ bnb, float* __restrict__ out) {
  int idx = blockIdx.x * blockDim.x + threadIdx.x;
  if (idx < kN * kD) {
    int d = idx & 63;
    float m = bnsum[d] * (1.f / (float)kN);
    float var = bnss[d] * (1.f / (float)kN) - m * m;
    float sc = rsqrtf(var + 1e-5f) * bng[d];
    out[idx] = (h[idx] - m) * sc + bnb[d];
  }
}

extern "C" void kernel_launch(void* const* d_in, const int* in_sizes, int n_in,
                              void* d_out, int out_size, void* d_ws, size_t ws_size,
                              hipStream_t stream) {
  const float* atom_x       = (const float*)d_in[0];
  const int*   atom_feature = (const int*)d_in[1];
  const int*   edge_index   = (const int*)d_in[2];
  const float* edge_attr    = (const float*)d_in[3];
  const float* atom_emb     = (const float*)d_in[4];
  const float* proj_W       = (const float*)d_in[5];
  const float* proj_b       = (const float*)d_in[6];
  const float* lin_W        = (const float*)d_in[7];
  const float* lin_b        = (const float*)d_in[8];
  const float* root_emb     = (const float*)d_in[9];
  const float* bond_W       = (const float*)d_in[10];
  const float* bond_b       = (const float*)d_in[11];
  const float* bond_g       = (const float*)d_in[12];
  const float* bond_beta    = (const float*)d_in[13];
  const float* gru_Wih      = (const float*)d_in[14];
  const float* gru_bih      = (const float*)d_in[15];
  const float* gru_Whh      = (const float*)d_in[16];
  const float* gru_bhh      = (const float*)d_in[17];
  const float* bn_g         = (const float*)d_in[18];
  const float* bn_b         = (const float*)d_in[19];
  float* out = (float*)d_out;

  const int* row = edge_index;
  const int* col = edge_index + kE;

  float* ws = (float*)d_ws;
  const size_t NH = (size_t)kN * kD;
  float* h     = ws;
  float* x     = ws + NH;
  float* aggr  = ws + 2 * NH;
  float* degf  = ws + 3 * NH;           // kN
  float* dinv  = degf + kN;             // kN
  int*   cntr  = (int*)(dinv + kN);     // kN
  int*   cntc  = cntr + kN;             // kN
  int*   ptr   = cntc + kN;             // kN+1
  int*   fill  = ptr + kN + 2;          // kN
  int*   loc   = fill + kN;             // kN
  int*   bsum  = loc + kN;              // 128
  int*   boff  = bsum + 128;            // 128
  int2*  re    = (int2*)(boff + 128);   // kE int2 (offset even -> 8B aligned)
  float* sumA  = (float*)(re + kE);     // 16
  float* Msum  = sumA + 16;             // 256
  float* Weff  = Msum + 256;            // 3*1024
  float* beff  = Weff + 3 * 1024;       // 192
  float* bnsum = beff + 192;            // 64
  float* bnss  = bnsum + 64;            // 64

  hipMemsetAsync(cntr, 0, 2 * kN * sizeof(int), stream);
  k_cnt<<<(kE + 255) / 256, 256, 0, stream>>>(row, col, cntr, cntc);
  k_dinv<<<(kN + 255) / 256, 256, 0, stream>>>(cntr, degf, dinv);
  k_scanA<<<kScanBlocks, 1024, 0, stream>>>(cntc, loc, bsum);
  k_scanB<<<1, 128, 0, stream>>>(bsum, boff);
  k_scanC<<<kScanBlocks, 1024, 0, stream>>>(loc, boff, ptr, fill);
  k_scatter<<<(kE + 255) / 256, 256, 0, stream>>>(row, col, fill, re);

  hipMemsetAsync(sumA, 0, (16 + 256) * sizeof(float), stream);
  k_stats<<<512, 256, 0, stream>>>(edge_attr, sumA, Msum);
  k_bnfold<<<1, 256, 0, stream>>>(sumA, Msum, bond_W, bond_b, bond_g, bond_beta,
                                  Weff, beff);
  k_enc<<<1024, 256, 0, stream>>>(atom_x, atom_feature, atom_emb, proj_W, proj_b, h);

  for (int l = 0; l < 3; l++) {
    const float* pg = (l > 0) ? (bn_g + (l - 1) * 64) : bn_g;
    const float* pb = (l > 0) ? (bn_b + (l - 1) * 64) : bn_b;
    k_lin<<<1024, 256, 0, stream>>>(h, lin_W + l * 64 * 64, lin_b + l * 64,
                                    l > 0 ? 1 : 0, bnsum, bnss, pg, pb, x);
    k_aggr<<<(kN + 3) / 4, 256, 0, stream>>>(ptr, re, edge_attr, x, dinv,
                                             Weff + l * 1024, beff + l * 64, aggr);
    hipMemsetAsync(bnsum, 0, 128 * sizeof(float), stream);
    k_gru<<<256, 1024, 0, stream>>>(aggr, x, gru_Wih + l * 192 * 64,
                                    gru_Whh + l * 192 * 64, gru_bih + l * 192,
                                    gru_bhh + l * 192, root_emb + l * 64, degf, h,
                                    bnsum, bnss);
  }
  k_final<<<(kN * kD + 255) / 256, 256, 0, stream>>>(h, bnsum, bnss, bn_g + 2 * 64,
                                                     bn_b + 2 * 64, out);
}

// Round 4
// 1460.740 us; speedup vs baseline: 1.4402x; 1.1279x over previous
//
#include <hip/hip_runtime.h>
#include <hip/hip_bf16.h>

constexpr int kN    = 100000;
constexpr int kE    = 1600000;
constexpr int kD    = 64;
constexpr int kNF   = 9;
constexpr int kCARD = 16;
constexpr int kBF   = 16;
constexpr int kScanBlocks = (kN + 1023) / 1024;  // 98

typedef __bf16 bf16x8 __attribute__((ext_vector_type(8)));
typedef float f32x4 __attribute__((ext_vector_type(4)));
union BF8 { unsigned u[4]; bf16x8 v; };

__device__ __forceinline__ float lane_bcast(float v, int k) {
  return __uint_as_float((unsigned)__builtin_amdgcn_readlane((int)__float_as_uint(v), k));
}
__device__ __forceinline__ float sigm(float v) { return 1.f / (1.f + __expf(-v)); }
__device__ __forceinline__ float tanh_f(float v) { return 1.f - 2.f / (__expf(2.f * v) + 1.f); }

__device__ __forceinline__ unsigned bf16_bits(float v) {
  unsigned u = __float_as_uint(v);
  return (u + 0x7fffu + ((u >> 16) & 1u)) >> 16;
}
__device__ __forceinline__ unsigned pack_bf(float lo, float hi) {
  return bf16_bits(lo) | (bf16_bits(hi) << 16);
}

// ---------- degree counts (row for deg/dinv, col for CSR) ----------
__global__ void k_cnt(const int* __restrict__ row, const int* __restrict__ col,
                      int* __restrict__ cntr, int* __restrict__ cntc) {
  int e = blockIdx.x * blockDim.x + threadIdx.x;
  if (e < kE) {
    atomicAdd(&cntr[row[e]], 1);
    atomicAdd(&cntc[col[e]], 1);
  }
}

__global__ void k_dinv(const int* __restrict__ cnt, float* __restrict__ degf,
                       float* __restrict__ dinv) {
  int n = blockIdx.x * blockDim.x + threadIdx.x;
  if (n < kN) {
    float d = (float)cnt[n] + 1.f;
    degf[n] = d;
    dinv[n] = rsqrtf(d);
  }
}

// ---------- multi-block exclusive scan of col counts ----------
__global__ __launch_bounds__(1024) void k_scanA(const int* __restrict__ cnt,
                                                int* __restrict__ loc,
                                                int* __restrict__ bsum) {
  __shared__ int part[1024];
  int tid = threadIdx.x;
  int i = blockIdx.x * 1024 + tid;
  int v = (i < kN) ? cnt[i] : 0;
  part[tid] = v;
  __syncthreads();
  for (int off = 1; off < 1024; off <<= 1) {
    int t = (tid >= off) ? part[tid - off] : 0;
    __syncthreads();
    part[tid] += t;
    __syncthreads();
  }
  if (i < kN) loc[i] = part[tid] - v;  // local exclusive
  if (tid == 1023) bsum[blockIdx.x] = part[1023];
}

__global__ __launch_bounds__(128) void k_scanB(const int* __restrict__ bsum,
                                               int* __restrict__ boff) {
  __shared__ int p[128];
  int tid = threadIdx.x;
  int v = (tid < kScanBlocks) ? bsum[tid] : 0;
  p[tid] = v;
  __syncthreads();
  for (int off = 1; off < 128; off <<= 1) {
    int t = (tid >= off) ? p[tid - off] : 0;
    __syncthreads();
    p[tid] += t;
    __syncthreads();
  }
  boff[tid] = p[tid] - v;  // exclusive
}

__global__ __launch_bounds__(1024) void k_scanC(const int* __restrict__ loc,
                                                const int* __restrict__ boff,
                                                int* __restrict__ ptr,
                                                int* __restrict__ fill) {
  int i = blockIdx.x * 1024 + threadIdx.x;
  if (i < kN) {
    int v = loc[i] + boff[blockIdx.x];
    ptr[i] = v;
    fill[i] = v;
  }
  if (i == 0) ptr[kN] = kE;  // grand total is statically kE
}

// ---------- scatter (row, eid) into col-sorted order ----------
__global__ void k_scatter(const int* __restrict__ row, const int* __restrict__ col,
                          int* __restrict__ fill, int2* __restrict__ re) {
  int e = blockIdx.x * blockDim.x + threadIdx.x;
  if (e < kE) {
    int c = col[e];
    int p = atomicAdd(&fill[c], 1);
    re[p] = make_int2(row[e], e);
  }
}

// ---------- edge_attr moments: sumA[16], M = A^T A [16x16] ----------
__global__ __launch_bounds__(256) void k_stats(const float* __restrict__ ea,
                                               float* __restrict__ sumA,
                                               float* __restrict__ Msum) {
  __shared__ float tile[1024];
  int tid = threadIdx.x;
  int i = tid >> 4, j = tid & 15;
  float accM = 0.f, accS = 0.f;
  const int T = kE / 64;
  for (int t = blockIdx.x; t < T; t += gridDim.x) {
    const float4* src = (const float4*)(ea + (size_t)t * 1024);
    ((float4*)tile)[tid] = src[tid];
    __syncthreads();
#pragma unroll 8
    for (int e = 0; e < 64; e++) {
      float aj = tile[e * 16 + j];
      accM += tile[e * 16 + i] * aj;
      if (i == 0) accS += aj;
    }
    __syncthreads();
  }
  atomicAdd(&Msum[i * 16 + j], accM);
  if (i == 0) atomicAdd(&sumA[j], accS);
}

// ---------- fold bond-linear + BN into Weff/beff per layer ----------
__global__ __launch_bounds__(256) void k_bnfold(
    const float* __restrict__ sumA, const float* __restrict__ Msum,
    const float* __restrict__ bond_W, const float* __restrict__ bond_b,
    const float* __restrict__ bond_g, const float* __restrict__ bond_beta,
    float* __restrict__ Weff, float* __restrict__ beff) {
  __shared__ float Ms[256];
  __shared__ float ab[16];
  int tid = threadIdx.x;
  Ms[tid] = Msum[tid] * (1.f / (float)kE);
  if (tid < 16) ab[tid] = sumA[tid] * (1.f / (float)kE);
  __syncthreads();
  if (tid < 192) {
    int l = tid / 64, d = tid % 64;
    const float* W = bond_W + l * kBF * kD;
    float w[16];
#pragma unroll
    for (int k = 0; k < 16; k++) w[k] = W[k * 64 + d];
    float b = bond_b[l * 64 + d];
    float lin = 0.f;
#pragma unroll
    for (int k = 0; k < 16; k++) lin += ab[k] * w[k];
    float mu = lin + b;
    float q = 0.f;
#pragma unroll
    for (int i = 0; i < 16; i++) {
      float wi = w[i];
#pragma unroll
      for (int k = 0; k < 16; k++) q += Ms[i * 16 + k] * wi * w[k];
    }
    float ex2 = q + 2.f * b * lin + b * b;
    float var = ex2 - mu * mu;
    float s = bond_g[l * 64 + d] * rsqrtf(var + 1e-6f);
#pragma unroll
    for (int k = 0; k < 16; k++) Weff[l * 1024 + k * 64 + d] = w[k] * s;
    beff[l * 64 + d] = (b - mu) * s + bond_beta[l * 64 + d];
  }
}

// ---------- GRU weight prep: Bt[l][j][k] bf16, j in [0,256), k in [0,128) ----------
// cols j: [0,64) r-sum, [64,128) z-sum, [128,192) inn (x-half zero),
//         [192,256) hn (aggr-half zero). Input u = [aggr | x].
__global__ void k_wprep(const float* __restrict__ Wih, const float* __restrict__ Whh,
                        unsigned short* __restrict__ Bt) {
  int idx = blockIdx.x * 256 + threadIdx.x;
  if (idx >= 3 * 256 * 128) return;
  int l = idx / (256 * 128);
  int rem = idx % (256 * 128);
  int j = rem / 128, k = rem % 128;
  const float* ih = Wih + l * 192 * 64;
  const float* hh = Whh + l * 192 * 64;
  float v;
  if (j < 128)      v = (k < 64) ? ih[j * 64 + k] : hh[j * 64 + (k - 64)];
  else if (j < 192) v = (k < 64) ? ih[j * 64 + k] : 0.f;
  else              v = (k < 64) ? 0.f : hh[(j - 64) * 64 + (k - 64)];
  Bt[idx] = (unsigned short)bf16_bits(v);
}

// ---------- encoder: h = [atom_x, sum_f emb] @ projW + b ----------
__global__ __launch_bounds__(256) void k_enc(
    const float* __restrict__ atom_x, const int* __restrict__ feat,
    const float* __restrict__ emb, const float* __restrict__ projW,
    const float* __restrict__ projb, float* __restrict__ h) {
  __shared__ float W[128 * 64];
  int tid = threadIdx.x;
  for (int i = tid; i < 128 * 64 / 4; i += 256)
    ((float4*)W)[i] = ((const float4*)projW)[i];
  __syncthreads();
  int lane = tid & 63, wv = tid >> 6;
  int gw = blockIdx.x * 4 + wv, nw = gridDim.x * 4;
  float bd = projb[lane];
  for (int grp = gw; grp < kN / 4; grp += nw) {
    int n0 = grp * 4;
    float ax[4], x2[4], acc[4];
#pragma unroll
    for (int i = 0; i < 4; i++) {
      int n = n0 + i;
      ax[i] = atom_x[n * kD + lane];
      const int* fr = feat + n * kNF;
      float s = 0.f;
#pragma unroll
      for (int f = 0; f < kNF; f++) {
        int c = fr[f];
        s += emb[(f * kCARD + c) * kD + lane];
      }
      x2[i] = s;
      acc[i] = bd;
    }
#pragma unroll 4
    for (int k = 0; k < kD; k++) {
      float wt = W[k * 64 + lane];
      float wb = W[(64 + k) * 64 + lane];
#pragma unroll
      for (int i = 0; i < 4; i++)
        acc[i] += lane_bcast(ax[i], k) * wt + lane_bcast(x2[i], k) * wb;
    }
#pragma unroll
    for (int i = 0; i < 4; i++) h[(n0 + i) * kD + lane] = acc[i];
  }
}

// ---------- x = BN(h)[opt relu] @ lin_W + lin_b ----------
__global__ __launch_bounds__(256) void k_lin(
    const float* __restrict__ hin, const float* __restrict__ Wg,
    const float* __restrict__ bg, int apply_bn,
    const float* __restrict__ bnsum, const float* __restrict__ bnss,
    const float* __restrict__ bng, const float* __restrict__ bnb,
    float* __restrict__ xout) {
  __shared__ float W[64 * 64];
  int tid = threadIdx.x;
  for (int i = tid; i < 64 * 64 / 4; i += 256)
    ((float4*)W)[i] = ((const float4*)Wg)[i];
  __syncthreads();
  int lane = tid & 63, wv = tid >> 6;
  int gw = blockIdx.x * 4 + wv, nw = gridDim.x * 4;
  float mu = 0.f, sc = 0.f, bb = 0.f;
  if (apply_bn) {
    float m = bnsum[lane] * (1.f / (float)kN);
    float var = bnss[lane] * (1.f / (float)kN) - m * m;
    mu = m;
    sc = rsqrtf(var + 1e-5f) * bng[lane];
    bb = bnb[lane];
  }
  float bd = bg[lane];
  for (int grp = gw; grp < kN / 4; grp += nw) {
    int n0 = grp * 4;
    float hv[4], acc[4];
#pragma unroll
    for (int i = 0; i < 4; i++) {
      float v = hin[(n0 + i) * kD + lane];
      if (apply_bn) v = fmaxf((v - mu) * sc + bb, 0.f);
      hv[i] = v;
      acc[i] = bd;
    }
#pragma unroll 4
    for (int k = 0; k < kD; k++) {
      float w = W[k * 64 + lane];
#pragma unroll
      for (int i = 0; i < 4; i++) acc[i] += lane_bcast(hv[i], k) * w;
    }
#pragma unroll
    for (int i = 0; i < 4; i++) xout[(n0 + i) * kD + lane] = acc[i];
  }
}

// ---------- CSR gather: aggr[n] = sum_{e: col[e]=n} norm*relu(x[row]+bond) ----------
__global__ __launch_bounds__(256) void k_aggr(
    const int* __restrict__ ptr, const int2* __restrict__ re,
    const float* __restrict__ ea, const float* __restrict__ x,
    const float* __restrict__ dinv, const float* __restrict__ Weff,
    const float* __restrict__ beff, float* __restrict__ aggr) {
  int lane = threadIdx.x & 63, wv = threadIdx.x >> 6;
  int n = blockIdx.x * 4 + wv;
  if (n >= kN) return;
  float wc[16];
#pragma unroll
  for (int k = 0; k < 16; k++) wc[k] = Weff[k * 64 + lane];
  float be = beff[lane];
  int start = ptr[n], end = ptr[n + 1];
  float dc = dinv[n];
  float acc = 0.f;
  for (int j0 = start; j0 < end; j0 += 64) {
    int j = j0 + lane;
    int2 m = (j < end) ? re[j] : make_int2(0, 0);
    int cnt = min(64, end - j0);
    for (int t = 0; t < cnt; t++) {
      int rt = __builtin_amdgcn_readlane(m.x, t);
      int et = __builtin_amdgcn_readlane(m.y, t);
      float nrm = dc * dinv[rt];
      float xj = x[(size_t)rt * kD + lane];
      const float4* a4 = (const float4*)(ea + (size_t)et * kBF);
      float bond = be;
#pragma unroll
      for (int q = 0; q < 4; q++) {
        float4 a = a4[q];
        bond += a.x * wc[q * 4] + a.y * wc[q * 4 + 1] +
                a.z * wc[q * 4 + 2] + a.w * wc[q * 4 + 3];
      }
      acc += nrm * fmaxf(xj + bond, 0.f);
    }
  }
  aggr[(size_t)n * kD + lane] = acc;
}

// ---------- MFMA GRU: one [64-node,128] @ [128,256] GEMM per block + epilogue ----------
// u = [aggr | x] bf16; Bt cols: r-sum, z-sum, inn, hn. Wave w = M-tile w (16 nodes).
__global__ __launch_bounds__(256) void k_gru_mfma(
    const float* __restrict__ aggr, const float* __restrict__ x,
    const unsigned short* __restrict__ Bt,  // [256][128] bf16 for this layer
    const float* __restrict__ bih, const float* __restrict__ bhh,
    const float* __restrict__ root, const float* __restrict__ degf,
    float* __restrict__ h, float* __restrict__ bnsum, float* __restrict__ bnss) {
  __shared__ float sb[2][16][65];
  int tid = threadIdx.x;
  int wv = tid >> 6;
  int c = tid & 15;          // lane&15
  int q = (tid & 63) >> 4;   // quad
  int nbase = blockIdx.x * 64 + wv * 16;

  // A fragments: A[m = c][k = kk*32 + q*8 + j], u[k] = k<64 ? aggr : x
  int na = min(nbase + c, kN - 1);
  bf16x8 afrag[4];
#pragma unroll
  for (int kk = 0; kk < 4; kk++) {
    const float* src = (kk < 2) ? (aggr + (size_t)na * 64 + kk * 32 + q * 8)
                                : (x + (size_t)na * 64 + (kk - 2) * 32 + q * 8);
    float4 f0 = ((const float4*)src)[0];
    float4 f1 = ((const float4*)src)[1];
    BF8 t;
    t.u[0] = pack_bf(f0.x, f0.y);
    t.u[1] = pack_bf(f0.z, f0.w);
    t.u[2] = pack_bf(f1.x, f1.y);
    t.u[3] = pack_bf(f1.z, f1.w);
    afrag[kk] = t.v;
  }

  f32x4 acc[16];
#pragma unroll
  for (int jt = 0; jt < 16; jt++) {
    f32x4 a = {0.f, 0.f, 0.f, 0.f};
#pragma unroll
    for (int kk = 0; kk < 4; kk++) {
      // B[k = kk*32 + q*8 + j][n = jt*16 + c] = Bt[jt*16+c][kk*32+q*8+j]
      const bf16x8* bp =
          (const bf16x8*)(Bt + (size_t)(jt * 16 + c) * 128 + kk * 32 + q * 8);
      a = __builtin_amdgcn_mfma_f32_16x16x32_bf16(afrag[kk], *bp, a, 0, 0, 0);
    }
    acc[jt] = a;
  }

  // Epilogue: lane holds, for node n = nbase + q*4 + reg and d = jt4*16 + c:
  // r-pre = acc[jt4][reg], z-pre = acc[4+jt4][reg], inn = acc[8+jt4][reg], hn = acc[12+jt4][reg]
  float s1[4] = {0.f, 0.f, 0.f, 0.f}, s2[4] = {0.f, 0.f, 0.f, 0.f};
#pragma unroll
  for (int jt4 = 0; jt4 < 4; jt4++) {
    int d = jt4 * 16 + c;
    float br = bih[d] + bhh[d];
    float bz = bih[64 + d] + bhh[64 + d];
    float bin = bih[128 + d];
    float bhn = bhh[128 + d];
    float rt = root[d];
#pragma unroll
    for (int reg = 0; reg < 4; reg++) {
      int n = nbase + q * 4 + reg;
      if (n < kN) {
        float xv = x[(size_t)n * 64 + d];
        float r = sigm(acc[jt4][reg] + br);
        float z = sigm(acc[4 + jt4][reg] + bz);
        float nn = tanh_f(acc[8 + jt4][reg] + bin + r * (acc[12 + jt4][reg] + bhn));
        float upd = (1.f - z) * nn + z * xv;
        float hl = upd + fmaxf(xv + rt, 0.f) / degf[n];
        h[(size_t)n * 64 + d] = hl;
        s1[jt4] += hl;
        s2[jt4] += hl * hl;
      }
    }
  }

  // BN-stat reduction: row = wv*4 + q, col = d
  int rowi = wv * 4 + q;
#pragma unroll
  for (int jt4 = 0; jt4 < 4; jt4++) {
    sb[0][rowi][jt4 * 16 + c] = s1[jt4];
    sb[1][rowi][jt4 * 16 + c] = s2[jt4];
  }
  __syncthreads();
  if (tid < 64) {
    float t1 = 0.f, t2 = 0.f;
#pragma unroll
    for (int rr = 0; rr < 16; rr++) {
      t1 += sb[0][rr][tid];
      t2 += sb[1][rr][tid];
    }
    atomicAdd(&bnsum[tid], t1);
    atomicAdd(&bnss[tid], t2);
  }
}

// ---------- final BN (layer 2, no relu) -> d_out ----------
__global__ void k_final(const float* __restrict__ h, const float* __restrict__ bnsum,
                        const float* __restrict__ bnss, const float* __restrict__ bng,
                        const float* __restrict__ bnb, float* __restrict__ out) {
  int idx = blockIdx.x * blockDim.x + threadIdx.x;
  if (idx < kN * kD) {
    int d = idx & 63;
    float m = bnsum[d] * (1.f / (float)kN);
    float var = bnss[d] * (1.f / (float)kN) - m * m;
    float sc = rsqrtf(var + 1e-5f) * bng[d];
    out[idx] = (h[idx] - m) * sc + bnb[d];
  }
}

extern "C" void kernel_launch(void* const* d_in, const int* in_sizes, int n_in,
                              void* d_out, int out_size, void* d_ws, size_t ws_size,
                              hipStream_t stream) {
  const float* atom_x       = (const float*)d_in[0];
  const int*   atom_feature = (const int*)d_in[1];
  const int*   edge_index   = (const int*)d_in[2];
  const float* edge_attr    = (const float*)d_in[3];
  const float* atom_emb     = (const float*)d_in[4];
  const float* proj_W       = (const float*)d_in[5];
  const float* proj_b       = (const float*)d_in[6];
  const float* lin_W        = (const float*)d_in[7];
  const float* lin_b        = (const float*)d_in[8];
  const float* root_emb     = (const float*)d_in[9];
  const float* bond_W       = (const float*)d_in[10];
  const float* bond_b       = (const float*)d_in[11];
  const float* bond_g       = (const float*)d_in[12];
  const float* bond_beta    = (const float*)d_in[13];
  const float* gru_Wih      = (const float*)d_in[14];
  const float* gru_bih      = (const float*)d_in[15];
  const float* gru_Whh      = (const float*)d_in[16];
  const float* gru_bhh      = (const float*)d_in[17];
  const float* bn_g         = (const float*)d_in[18];
  const float* bn_b         = (const float*)d_in[19];
  float* out = (float*)d_out;

  const int* row = edge_index;
  const int* col = edge_index + kE;

  float* ws = (float*)d_ws;
  const size_t NH = (size_t)kN * kD;
  float* h     = ws;
  float* x     = ws + NH;
  float* aggr  = ws + 2 * NH;
  float* degf  = ws + 3 * NH;           // kN
  float* dinv  = degf + kN;             // kN
  int*   cntr  = (int*)(dinv + kN);     // kN
  int*   cntc  = cntr + kN;             // kN
  int*   ptr   = cntc + kN;             // kN+1
  int*   fill  = ptr + kN + 2;          // kN
  int*   loc   = fill + kN;             // kN
  int*   bsum  = loc + kN;              // 128
  int*   boff  = bsum + 128;            // 128
  int2*  re    = (int2*)(boff + 128);   // kE int2 (offset even -> 8B aligned)
  float* sumA  = (float*)(re + kE);     // 16
  float* Msum  = sumA + 16;             // 256
  float* Weff  = Msum + 256;            // 3*1024
  float* beff  = Weff + 3 * 1024;       // 192
  float* bnsum = beff + 192;            // 64
  float* bnss  = bnsum + 64;            // 64
  unsigned short* Bt = (unsigned short*)(bnss + 64);  // 3*256*128 bf16

  hipMemsetAsync(cntr, 0, 2 * kN * sizeof(int), stream);
  k_cnt<<<(kE + 255) / 256, 256, 0, stream>>>(row, col, cntr, cntc);
  k_dinv<<<(kN + 255) / 256, 256, 0, stream>>>(cntr, degf, dinv);
  k_scanA<<<kScanBlocks, 1024, 0, stream>>>(cntc, loc, bsum);
  k_scanB<<<1, 128, 0, stream>>>(bsum, boff);
  k_scanC<<<kScanBlocks, 1024, 0, stream>>>(loc, boff, ptr, fill);
  k_scatter<<<(kE + 255) / 256, 256, 0, stream>>>(row, col, fill, re);

  hipMemsetAsync(sumA, 0, (16 + 256) * sizeof(float), stream);
  k_stats<<<512, 256, 0, stream>>>(edge_attr, sumA, Msum);
  k_bnfold<<<1, 256, 0, stream>>>(sumA, Msum, bond_W, bond_b, bond_g, bond_beta,
                                  Weff, beff);
  k_wprep<<<(3 * 256 * 128 + 255) / 256, 256, 0, stream>>>(gru_Wih, gru_Whh, Bt);
  k_enc<<<1024, 256, 0, stream>>>(atom_x, atom_feature, atom_emb, proj_W, proj_b, h);

  for (int l = 0; l < 3; l++) {
    const float* pg = (l > 0) ? (bn_g + (l - 1) * 64) : bn_g;
    const float* pb = (l > 0) ? (bn_b + (l - 1) * 64) : bn_b;
    k_lin<<<1024, 256, 0, stream>>>(h, lin_W + l * 64 * 64, lin_b + l * 64,
                                    l > 0 ? 1 : 0, bnsum, bnss, pg, pb, x);
    k_aggr<<<(kN + 3) / 4, 256, 0, stream>>>(ptr, re, edge_attr, x, dinv,
                                             Weff + l * 1024, beff + l * 64, aggr);
    hipMemsetAsync(bnsum, 0, 128 * sizeof(float), stream);
    k_gru_mfma<<<(kN + 63) / 64, 256, 0, stream>>>(
        aggr, x, Bt + (size_t)l * 256 * 128, gru_bih + l * 192, gru_bhh + l * 192,
        root_emb + l * 64, degf, h, bnsum, bnss);
  }
  k_final<<<(kN * kD + 255) / 256, 256, 0, stream>>>(h, bnsum, bnss, bn_g + 2 * 64,
                                                     bn_b + 2 * 64, out);
}